// Round 11
// baseline (72212.970 us; speedup 1.0000x reference)
//
#include <hip/hip_runtime.h>
#include <hip/hip_fp16.h>

#define NB 64
#define NT 1000
#define NH 512
#define NI 32
#define NO 32
#define ALPHA 0.05f
#define NOISE_STD 0.05f

#define LDW 76            // dwords per LDS column -> 152 rows (155.6 KB, proven R8 size)
#define LDSROWS 152
#define AGU 45            // AGPR uint4 units -> 360 rows [152,512)

typedef unsigned int uint32;
typedef __attribute__((ext_vector_type(2))) _Float16 half2v;

static __device__ __forceinline__ float dot2f(uint32 a, uint32 b, float c) {
#if __has_builtin(__builtin_amdgcn_fdot2)
    return __builtin_amdgcn_fdot2(__builtin_bit_cast(half2v, a),
                                  __builtin_bit_cast(half2v, b), c, false);
#else
    half2v av = __builtin_bit_cast(half2v, a);
    half2v bv = __builtin_bit_cast(half2v, b);
    return c + (float)av[0] * (float)bv[0] + (float)av[1] * (float)bv[1];
#endif
}

static __device__ __forceinline__ uint32 pack2(float a, float b) {
    __half2 hp = __floats2half2_rn(a, b);
    return *(uint32*)&hp;
}

#define REP45(F) F(0) F(1) F(2) F(3) F(4) F(5) F(6) F(7) F(8) F(9) \
    F(10) F(11) F(12) F(13) F(14) F(15) F(16) F(17) F(18) F(19) \
    F(20) F(21) F(22) F(23) F(24) F(25) F(26) F(27) F(28) F(29) \
    F(30) F(31) F(32) F(33) F(34) F(35) F(36) F(37) F(38) F(39) \
    F(40) F(41) F(42) F(43) F(44)

// --------- precompute c[b][t][j] = NOISE_STD*noise + (ALPHA/tM_j)*(x_t @ wi)_j  (f16) ---------
__global__ __launch_bounds__(512) void precompute_c_kernel(
    const float* __restrict__ x, const float* __restrict__ noise,
    const float* __restrict__ wi, const float* __restrict__ tM,
    __half* __restrict__ cbuf)
{
    const int bt = blockIdx.x;      // b*NT + t
    const int j = threadIdx.x;
    __shared__ float xs[NI];
    if (j < NI) xs[j] = x[(size_t)bt * NI + j];
    __syncthreads();
    const float a_inv = ALPHA * (1.0f / tM[j]);
    const float nv = noise[(size_t)bt * NH + j];
    float xw = 0.f;
    #pragma unroll
    for (int i = 0; i < NI; ++i) xw += xs[i] * wi[i * NH + j];
    cbuf[(size_t)bt * NH + j] = __float2half(NOISE_STD * nv + a_inv * xw);
}

// One WG (512 thr) per batch. Thread j owns column j of W' = (alpha/tM_j*g_j)*wrec.
// Rows [0,152) in LDS; rows [152,512) PINNED IN AGPRs via inline-asm accvgpr
// write/read — the register allocator cannot spill or rematerialize them.
__global__
__attribute__((amdgpu_flat_work_group_size(512, 512), amdgpu_waves_per_eu(2, 2)))
void rnn_agpr_kernel(
    const float* __restrict__ wrec, const float* __restrict__ wout,
    const float* __restrict__ bias, const float* __restrict__ g,
    const float* __restrict__ tM, const float* __restrict__ h0,
    const __half* __restrict__ cbuf, float* __restrict__ out)
{
    __shared__ __align__(16) uint32 wl[NH * LDW];    // 155.6 KB: W' rows [0,152)
    __shared__ __align__(16) uint32 r32[NH / 2];     // 1 KB: r(t) f16 pairs

    const int b = blockIdx.x;
    const int j = threadIdx.x;
    const int w = j >> 6, l = j & 63;

    const float a_inv = ALPHA / tM[j];
    const float scale = a_inv * g[j];
    const float hs1 = 1.0f - a_inv;
    const float hb = a_inv * bias[j];
    float h = h0[j];

    // ---- stage W' rows [0,152) into LDS (stride-76 rotates banks naturally) ----
    #pragma unroll
    for (int u = 0; u < LDW; ++u)
        wl[j * LDW + u] = pack2(scale * wrec[(size_t)(2 * u) * NH + j],
                                scale * wrec[(size_t)(2 * u + 1) * NH + j]);

    // ---- pin W' rows [152,512) into AGPRs: 45 units x 4 dwords ----
#define DECLA(n) uint32 A##n##_0, A##n##_1, A##n##_2, A##n##_3;
    REP45(DECLA)
#undef DECLA
#define LOADA(n) { \
    const int base = LDSROWS + 8 * (n); \
    uint32 v0 = pack2(scale * wrec[(size_t)(base + 0) * NH + j], \
                      scale * wrec[(size_t)(base + 1) * NH + j]); \
    uint32 v1 = pack2(scale * wrec[(size_t)(base + 2) * NH + j], \
                      scale * wrec[(size_t)(base + 3) * NH + j]); \
    uint32 v2 = pack2(scale * wrec[(size_t)(base + 4) * NH + j], \
                      scale * wrec[(size_t)(base + 5) * NH + j]); \
    uint32 v3 = pack2(scale * wrec[(size_t)(base + 6) * NH + j], \
                      scale * wrec[(size_t)(base + 7) * NH + j]); \
    asm volatile("v_accvgpr_write_b32 %0, %1" : "=a"(A##n##_0) : "v"(v0)); \
    asm volatile("v_accvgpr_write_b32 %0, %1" : "=a"(A##n##_1) : "v"(v1)); \
    asm volatile("v_accvgpr_write_b32 %0, %1" : "=a"(A##n##_2) : "v"(v2)); \
    asm volatile("v_accvgpr_write_b32 %0, %1" : "=a"(A##n##_3) : "v"(v3)); \
    __builtin_amdgcn_sched_barrier(0); }
    REP45(LOADA)
#undef LOADA

    // ---- wout in 16 named regs: wave w -> cols 4w..4w+3; lane l -> rows [8l,8l+8) ----
    uint32 wor00, wor01, wor02, wor03, wor10, wor11, wor12, wor13;
    uint32 wor20, wor21, wor22, wor23, wor30, wor31, wor32, wor33;
#define LW(cc, uu) pack2(wout[(size_t)(8 * l + 2 * (uu)) * NO + 4 * w + (cc)], \
                         wout[(size_t)(8 * l + 2 * (uu) + 1) * NO + 4 * w + (cc)])
    wor00 = LW(0,0); wor01 = LW(0,1); wor02 = LW(0,2); wor03 = LW(0,3);
    wor10 = LW(1,0); wor11 = LW(1,1); wor12 = LW(1,2); wor13 = LW(1,3);
    wor20 = LW(2,0); wor21 = LW(2,1); wor22 = LW(2,2); wor23 = LW(2,3);
    wor30 = LW(3,0); wor31 = LW(3,1); wor32 = LW(3,2); wor33 = LW(3,3);
#undef LW

    __syncthreads();

    const __half* cp = cbuf + (size_t)b * NT * NH + j;
    float* outp      = out + (size_t)b * NT * NO;

    for (int t = 0; t < NT; ++t) {
        // r(t) = relu(h) -> LDS f16
        ((unsigned short*)r32)[j] = __half_as_ushort(__float2half(fmaxf(h, 0.f)));
        __syncthreads();

        // per-step additive term (hides under matvec)
        const float cval = __half2float(cp[(size_t)t * NH]);

        float a0 = 0.f, a1 = 0.f, a2 = 0.f, a3 = 0.f;
        // matvec rows [0,152) from LDS
        #pragma unroll
        for (int U = 0; U < 19; ++U) {
            const uint4 rr = *(const uint4*)(r32 + 4 * U);          // broadcast
            const uint4 ww = *(const uint4*)(wl + j * LDW + 4 * U);
            a0 = dot2f(ww.x, rr.x, a0); a1 = dot2f(ww.y, rr.y, a1);
            a2 = dot2f(ww.z, rr.z, a2); a3 = dot2f(ww.w, rr.w, a3);
        }
        // rows [152,512) from AGPR-pinned weights
#define MACA(n) { \
    uint32 t0, t1, t2, t3; \
    asm volatile("v_accvgpr_read_b32 %0, %4\n\t" \
                 "v_accvgpr_read_b32 %1, %5\n\t" \
                 "v_accvgpr_read_b32 %2, %6\n\t" \
                 "v_accvgpr_read_b32 %3, %7" \
        : "=v"(t0), "=v"(t1), "=v"(t2), "=v"(t3) \
        : "a"(A##n##_0), "a"(A##n##_1), "a"(A##n##_2), "a"(A##n##_3)); \
    const uint4 rr = *(const uint4*)(r32 + LDW + 4 * (n)); \
    a0 = dot2f(t0, rr.x, a0); a1 = dot2f(t1, rr.y, a1); \
    a2 = dot2f(t2, rr.z, a2); a3 = dot2f(t3, rr.w, a3); }
        REP45(MACA)
#undef MACA
        const float acc = (a0 + a1) + (a2 + a3);

        // out-projection for row t: wave w covers cols 4w..4w+3
        {
            const uint4 rr = *(const uint4*)(r32 + 4 * l);          // rows 8l..8l+8
#define OPROJ(c, w0, w1, w2, w3) { \
    float oa = dot2f(w0, rr.x, 0.f); \
    oa = dot2f(w1, rr.y, oa); \
    oa = dot2f(w2, rr.z, oa); \
    oa = dot2f(w3, rr.w, oa); \
    oa += __shfl_xor(oa, 1, 64);  oa += __shfl_xor(oa, 2, 64); \
    oa += __shfl_xor(oa, 4, 64);  oa += __shfl_xor(oa, 8, 64); \
    oa += __shfl_xor(oa, 16, 64); oa += __shfl_xor(oa, 32, 64); \
    if (l == 0) outp[(size_t)t * NO + 4 * w + (c)] = oa; }
            OPROJ(0, wor00, wor01, wor02, wor03)
            OPROJ(1, wor10, wor11, wor12, wor13)
            OPROJ(2, wor20, wor21, wor22, wor23)
            OPROJ(3, wor30, wor31, wor32, wor33)
#undef OPROJ
        }

        // h <- h*(1-a) + a*b + [std*noise + a*(x@wi)] + a*g*(r@wrec)
        h = h * hs1 + hb + cval + acc;
        __syncthreads();   // protect r32 before next overwrite
    }
}

// --------- fallback (only if ws too small for cbuf) ---------
__global__ __launch_bounds__(1024, 1) void rnn_seq_kernel(
    const float* __restrict__ x, const float* __restrict__ noise,
    const float* __restrict__ wi, const float* __restrict__ wrec,
    const float* __restrict__ wout, const float* __restrict__ bias,
    const float* __restrict__ g, const float* __restrict__ tM,
    const float* __restrict__ h0, float* __restrict__ out)
{
    const int bidx = blockIdx.x;
    const int tid  = threadIdx.x;
    const int j    = tid & (NH - 1);
    const int half = tid >> 9;

    __shared__ float hs[NH];
    __shared__ float rs[NH];
    __shared__ float accb[NH];
    __shared__ float xt[NI];
    __shared__ float red[32][NO + 1];

    float a_inv = 0.f, gj = 0.f, bj = 0.f;
    if (tid < NH) {
        hs[tid] = h0[tid];
        a_inv   = ALPHA / tM[tid];
        gj      = g[tid];
        bj      = bias[tid];
    }
    __syncthreads();

    const int k   = tid & (NO - 1);
    const int seg = tid >> 5;

    for (int t = 0; t < NT; ++t) {
        if (tid < NH) rs[tid] = fmaxf(hs[tid], 0.f);
        if (t < NT - 1 && tid >= NH && tid < NH + NI)
            xt[tid - NH] = x[((size_t)bidx * NT + t) * NI + (tid - NH)];
        __syncthreads();

        float nv = 0.f;
        if (t < NT - 1 && tid < NH)
            nv = noise[((size_t)bidx * NT + t) * NH + tid];

        {
            float pp = 0.f;
            const int base = seg * 16;
            #pragma unroll
            for (int m = 0; m < 16; ++m)
                pp += rs[base + m] * wout[(base + m) * NO + k];
            red[seg][k] = pp;
        }

        float acc = 0.f;
        if (t < NT - 1) {
            const float* wrp = wrec + ((size_t)half * 256) * NH + j;
            const int rbase = half * 256;
            #pragma unroll 16
            for (int i = 0; i < 256; ++i)
                acc += rs[rbase + i] * wrp[(size_t)i * NH];
            if (half) accb[j] = acc;
        }
        __syncthreads();

        if (t < NT - 1 && tid < NH) {
            float accf = acc + accb[j];
            float xw = 0.f;
            #pragma unroll
            for (int i = 0; i < NI; ++i)
                xw += xt[i] * wi[i * NH + j];
            float hv = hs[j];
            hs[j] = hv + NOISE_STD * nv + a_inv * (-hv + gj * accf + bj + xw);
        }

        if (tid < NO) {
            float s = 0.f;
            #pragma unroll
            for (int sg = 0; sg < 32; ++sg) s += red[sg][tid];
            out[((size_t)bidx * NT + t) * NO + tid] = s;
        }
        __syncthreads();
    }
}

extern "C" void kernel_launch(void* const* d_in, const int* in_sizes, int n_in,
                              void* d_out, int out_size, void* d_ws, size_t ws_size,
                              hipStream_t stream) {
    const float* x     = (const float*)d_in[0];
    const float* noise = (const float*)d_in[1];
    const float* wi    = (const float*)d_in[2];
    const float* wrec  = (const float*)d_in[3];
    const float* wout  = (const float*)d_in[4];
    const float* bias  = (const float*)d_in[5];
    const float* g     = (const float*)d_in[6];
    const float* tM    = (const float*)d_in[7];
    const float* h0    = (const float*)d_in[8];
    float* out = (float*)d_out;

    const size_t cb_bytes = (size_t)NB * NT * NH * 2;   // 65,536,000

    if (ws_size >= cb_bytes) {
        __half* cbuf = (__half*)d_ws;
        precompute_c_kernel<<<NB * NT, 512, 0, stream>>>(x, noise, wi, tM, cbuf);
        rnn_agpr_kernel<<<NB, 512, 0, stream>>>(wrec, wout, bias, g, tM, h0, cbuf, out);
    } else {
        rnn_seq_kernel<<<NB, 1024, 0, stream>>>(x, noise, wi, wrec, wout, bias, g, tM, h0, out);
    }
}